// Round 16
// baseline (396.602 us; speedup 1.0000x reference)
//
#include <hip/hip_runtime.h>

#define HH 256       // hidden size
#define NB 64        // batch (segments)
#define ROWS 64      // rows per block tile
#define NTOT 262144  // NK == NC
#define THREADS 256  // 4 waves

typedef _Float16 half8 __attribute__((ext_vector_type(8)));
typedef _Float16 half4 __attribute__((ext_vector_type(4)));
typedef float f32x4 __attribute__((ext_vector_type(4)));

// act LDS tile: [row][k] fp16, 64 rows x 256 k = 32KB, row stride 512B.
__device__ __forceinline__ uint32_t swz(uint32_t r, uint32_t k) {
  return (((r << 9) + (k << 1)) ^ ((r & 7) << 4)) ^ ((r & 8) << 3);
}

// ---------------------------------------------------------------------------
// Heavy layer via MFMA, swapped operands: D[j][r] = sum_k WT[j][k]*act[r][k]
// *** R16: act PING-PONG *** — layer reads `src`, epilogue writes `dst`
// (different buffer) -> no overwrite race -> ONE barrier per layer, and a
// wave enters its epilogue as soon as its own MFMAs retire (no read-drain).
// A streamed directly from WT in L2 (R7-proven no-spill loop: acc[4][4],
// unroll 2, ONE a-frag live inside the jf loop).
// Wave tile 64r x 64j (j0 = wid*64) -> W read exactly once per block-layer.
// MODE: 0 relu; 1 plain (trunk c); 2 multiply seg_mean[seg_g[r]] (branch)
// ---------------------------------------------------------------------------
template<int MODE>
__device__ __forceinline__ void heavy_layer(const char* src, char* dst,
                                            const _Float16* __restrict__ WT,
                                            const float* __restrict__ bias,
                                            const float* __restrict__ seg_mean,
                                            const int* __restrict__ seg_g, int tid)
{
  const int wid  = tid >> 6;
  const int lane = tid & 63;
  const int lr   = lane & 15;
  const int lg   = lane >> 4;
  const int j0   = wid << 6;

  f32x4 acc[4][4];  // [jf][rf]
#pragma unroll
  for (int jf = 0; jf < 4; ++jf)
#pragma unroll
    for (int rf = 0; rf < 4; ++rf)
      acc[jf][rf] = (f32x4){0.f, 0.f, 0.f, 0.f};

  const _Float16* wbase = WT + (j0 + lr) * HH + lg * 8;

#pragma unroll 2
  for (int ks = 0; ks < 8; ++ks) {
    half8 b[4];
#pragma unroll
    for (int rf = 0; rf < 4; ++rf)
      b[rf] = *(const half8*)(src + swz(rf * 16 + lr, ks * 32 + lg * 8));
#pragma unroll
    for (int jf = 0; jf < 4; ++jf) {
      half8 a = *(const half8*)(wbase + jf * 16 * HH + ks * 32);
#pragma unroll
      for (int rf = 0; rf < 4; ++rf)
        acc[jf][rf] = __builtin_amdgcn_mfma_f32_16x16x32_f16(a, b[rf], acc[jf][rf], 0, 0, 0);
    }
  }

  int sseg[4];
  if (MODE == 2) {
#pragma unroll
    for (int rf = 0; rf < 4; ++rf) sseg[rf] = seg_g[rf * 16 + lr];
  }

  // epilogue writes DST — no barrier needed before it (src untouched).
#pragma unroll
  for (int jf = 0; jf < 4; ++jf) {
    f32x4 bj = *(const f32x4*)(bias + j0 + jf * 16 + lg * 4);
#pragma unroll
    for (int rf = 0; rf < 4; ++rf) {
      f32x4 v = acc[jf][rf] + bj;
      if (MODE == 2) {
        f32x4 sm = *(const f32x4*)(seg_mean + sseg[rf] * HH + j0 + jf * 16 + lg * 4);
        v *= sm;
      }
      half4 h;
#pragma unroll
      for (int u = 0; u < 4; ++u) {
        float x = v[u];
        if (MODE == 0) x = fmaxf(x, 0.f);
        h[u] = (_Float16)x;
      }
      *(half4*)(dst + swz(rf * 16 + lr, j0 + jf * 16 + lg * 4)) = h;
    }
  }
  __syncthreads();  // dst complete for next layer (ONLY barrier this layer)
}

// layer 1 via MFMA: F=3 -> H (relu), K padded 3 -> 32 with zeros.
__device__ __forceinline__ void layer1_mfma(char* dst, const float* __restrict__ x,
                                            int r0g, const float* __restrict__ W0,
                                            const float* __restrict__ b0, int tid)
{
  const int wid  = tid >> 6;
  const int lane = tid & 63;
  const int lr   = lane & 15;
  const int lg   = lane >> 4;
  const int j0   = wid << 6;

  half8 a[4];
#pragma unroll
  for (int jf = 0; jf < 4; ++jf) {
    half8 v = {0, 0, 0, 0, 0, 0, 0, 0};
    if (lg == 0) {
      int j = j0 + jf * 16 + lr;
      v[0] = (_Float16)W0[j];
      v[1] = (_Float16)W0[HH + j];
      v[2] = (_Float16)W0[2 * HH + j];
    }
    a[jf] = v;
  }

  f32x4 acc[4][4];
#pragma unroll
  for (int jf = 0; jf < 4; ++jf)
#pragma unroll
    for (int rf = 0; rf < 4; ++rf)
      acc[jf][rf] = (f32x4){0.f, 0.f, 0.f, 0.f};

#pragma unroll
  for (int rf = 0; rf < 4; ++rf) {
    half8 b = {0, 0, 0, 0, 0, 0, 0, 0};
    if (lg == 0) {
      const float* xp = x + (size_t)(r0g + rf * 16 + lr) * 3;
      b[0] = (_Float16)xp[0];
      b[1] = (_Float16)xp[1];
      b[2] = (_Float16)xp[2];
    }
#pragma unroll
    for (int jf = 0; jf < 4; ++jf)
      acc[jf][rf] = __builtin_amdgcn_mfma_f32_16x16x32_f16(a[jf], b, acc[jf][rf], 0, 0, 0);
  }

#pragma unroll
  for (int jf = 0; jf < 4; ++jf) {
    f32x4 bj = *(const f32x4*)(b0 + j0 + jf * 16 + lg * 4);
#pragma unroll
    for (int rf = 0; rf < 4; ++rf) {
      f32x4 v = acc[jf][rf] + bj;
      half4 h;
#pragma unroll
      for (int u = 0; u < 4; ++u)
        h[u] = (_Float16)fmaxf(v[u], 0.f);
      *(half4*)(dst + swz(rf * 16 + lr, j0 + jf * 16 + lg * 4)) = h;
    }
  }
  __syncthreads();
}

// ---------------------------------------------------------------------------
__global__ __launch_bounds__(THREADS, 2)
void trunk_kernel(const float* __restrict__ nodes, const int* __restrict__ coord_seg,
                  const float* __restrict__ tw0, const float* __restrict__ tb0,
                  const _Float16* __restrict__ wt1, const float* __restrict__ tb1,
                  const _Float16* __restrict__ wt2, const float* __restrict__ tb2,
                  float* __restrict__ seg_sum)
{
  __shared__ __align__(16) char actA[ROWS * HH * 2];  // 32KB
  __shared__ __align__(16) char actB[ROWS * HH * 2];  // 32KB
  const int tid = threadIdx.x;
  const int r0g = blockIdx.x * ROWS;

  layer1_mfma(actA, nodes, r0g, tw0, tb0, tid);
  heavy_layer<0>(actA, actB, wt1, tb1, nullptr, nullptr, tid);
  heavy_layer<1>(actB, actA, wt2, tb2, nullptr, nullptr, tid);  // c -> actA

  // per-segment sums of c; segs sorted -> most tiles single-segment.
  {
    const int j = tid;
    const int s_lo = coord_seg[r0g];
    const int s_hi = coord_seg[r0g + ROWS - 1];
    if (s_lo == s_hi) {
      float p = 0.f;
#pragma unroll 8
      for (int r = 0; r < ROWS; ++r)
        p += (float)*(const _Float16*)(actA + swz(r, j));
      atomicAdd(&seg_sum[s_lo * HH + j], p);
    } else {
      for (int s = s_lo; s <= s_hi; ++s) {
        float p = 0.f;
        for (int r = 0; r < ROWS; ++r)
          if (coord_seg[r0g + r] == s)
            p += (float)*(const _Float16*)(actA + swz(r, j));
        atomicAdd(&seg_sum[s * HH + j], p);
      }
    }
  }
}

__global__ __launch_bounds__(THREADS, 2)
void branch_kernel(const float* __restrict__ known_nodes, const int* __restrict__ known_seg,
                   const float* __restrict__ bw0, const float* __restrict__ bb0,
                   const _Float16* __restrict__ wt1, const float* __restrict__ bb1,
                   const _Float16* __restrict__ wt2, const float* __restrict__ bb2,
                   const float* __restrict__ seg_mean,
                   const _Float16* __restrict__ wto, const float* __restrict__ ob0,
                   const float* __restrict__ ow1, const float* __restrict__ ob1,
                   float* __restrict__ out)
{
  __shared__ __align__(16) char actA[ROWS * HH * 2];  // 32KB
  __shared__ __align__(16) char actB[ROWS * HH * 2];  // 32KB
  __shared__ float ps[4 * ROWS * 3];                  // tail partials, 3KB
  const int tid = threadIdx.x;
  const int r0g = blockIdx.x * ROWS;

  layer1_mfma(actA, known_nodes, r0g, bw0, bb0, tid);
  heavy_layer<0>(actA, actB, wt1, bb1, nullptr, nullptr, tid);
  heavy_layer<2>(actB, actA, wt2, bb2, seg_mean, known_seg + r0g, tid);  // feat -> A
  heavy_layer<0>(actA, actB, wto, ob0, nullptr, nullptr, tid);           // h -> B

  // out = h @ ow1 + ob1 (256 -> 3): 256 threads, 4 k-quarters in parallel
  {
    const int r = tid & 63;
    const int q = tid >> 6;
    float o0 = 0.f, o1 = 0.f, o2 = 0.f;
    for (int kk = 0; kk < 64; kk += 8) {
      int k0 = q * 64 + kk;
      half8 h = *(const half8*)(actB + swz(r, k0));
#pragma unroll
      for (int u = 0; u < 8; ++u) {
        float a = (float)h[u];
        o0 = fmaf(a, ow1[(k0 + u) * 3 + 0], o0);
        o1 = fmaf(a, ow1[(k0 + u) * 3 + 1], o1);
        o2 = fmaf(a, ow1[(k0 + u) * 3 + 2], o2);
      }
    }
    float* p = ps + q * ROWS * 3;
    p[r * 3 + 0] = o0; p[r * 3 + 1] = o1; p[r * 3 + 2] = o2;
  }
  __syncthreads();
  if (tid < ROWS) {
    const int r = tid;
    float* dst = out + (size_t)(r0g + r) * 3;
#pragma unroll
    for (int c = 0; c < 3; ++c) {
      float o = ob1[c];
#pragma unroll
      for (int q = 0; q < 4; ++q) o += ps[q * ROWS * 3 + r * 3 + c];
      dst[c] = o;
    }
  }
}

// W[256][256] fp32 row-major -> WT[j][k] fp16 (5 matrices), once per launch.
struct WPtrs { const float* w[5]; _Float16* wt[5]; };
__global__ void transpose_kernel(WPtrs p)
{
  const int m = blockIdx.x >> 8;   // matrix
  const int j = blockIdx.x & 255;  // output row
  const int k = threadIdx.x;       // 256 threads, coalesced writes
  p.wt[m][j * HH + k] = (_Float16)p.w[m][k * HH + j];
}

__global__ void zero_kernel(float* __restrict__ p, int n)
{
  int i = blockIdx.x * blockDim.x + threadIdx.x;
  if (i < n) p[i] = 0.f;
}

__global__ void mean_kernel(const float* __restrict__ seg_sum,
                            const int* __restrict__ coord_seg,
                            float* __restrict__ seg_mean)
{
  const int b = blockIdx.x;
  int lo = 0, n = NTOT;
  while (n > 0) { int h = n >> 1; int mid = lo + h;
    if (coord_seg[mid] < b) { lo = mid + 1; n -= h + 1; } else n = h; }
  int hi = lo; n = NTOT - lo;
  while (n > 0) { int h = n >> 1; int mid = hi + h;
    if (coord_seg[mid] < b + 1) { hi = mid + 1; n -= h + 1; } else n = h; }
  float inv = 1.0f / fmaxf((float)(hi - lo), 1.0f);
  seg_mean[b * HH + threadIdx.x] = seg_sum[b * HH + threadIdx.x] * inv;
}

// ---------------------------------------------------------------------------
extern "C" void kernel_launch(void* const* d_in, const int* in_sizes, int n_in,
                              void* d_out, int out_size, void* d_ws, size_t ws_size,
                              hipStream_t stream)
{
  const float* known_nodes = (const float*)d_in[0];
  const float* nodes       = (const float*)d_in[1];
  const int*   known_seg   = (const int*)d_in[2];
  const int*   coord_seg   = (const int*)d_in[3];
  const float* bw0 = (const float*)d_in[4];
  const float* bb0 = (const float*)d_in[5];
  const float* bw1 = (const float*)d_in[6];
  const float* bb1 = (const float*)d_in[7];
  const float* bw2 = (const float*)d_in[8];
  const float* bb2 = (const float*)d_in[9];
  const float* tw0 = (const float*)d_in[10];
  const float* tb0 = (const float*)d_in[11];
  const float* tw1 = (const float*)d_in[12];
  const float* tb1 = (const float*)d_in[13];
  const float* tw2 = (const float*)d_in[14];
  const float* tb2 = (const float*)d_in[15];
  const float* ow0 = (const float*)d_in[16];
  const float* ob0 = (const float*)d_in[17];
  const float* ow1 = (const float*)d_in[18];
  const float* ob1 = (const float*)d_in[19];

  float* out      = (float*)d_out;
  float* seg_sum  = (float*)d_ws;                        // [64][256] f32
  float* seg_mean = seg_sum + NB * HH;                   // [64][256] f32
  _Float16* wtb   = (_Float16*)((char*)d_ws + (size_t)2 * NB * HH * 4);
  _Float16* wt_tw1 = wtb + 0 * HH * HH;
  _Float16* wt_tw2 = wtb + 1 * HH * HH;
  _Float16* wt_bw1 = wtb + 2 * HH * HH;
  _Float16* wt_bw2 = wtb + 3 * HH * HH;
  _Float16* wt_ow0 = wtb + 4 * HH * HH;

  WPtrs wp;
  wp.w[0] = tw1; wp.wt[0] = wt_tw1;
  wp.w[1] = tw2; wp.wt[1] = wt_tw2;
  wp.w[2] = bw1; wp.wt[2] = wt_bw1;
  wp.w[3] = bw2; wp.wt[3] = wt_bw2;
  wp.w[4] = ow0; wp.wt[4] = wt_ow0;

  transpose_kernel<<<5 * 256, 256, 0, stream>>>(wp);
  zero_kernel<<<(NB * HH + 255) / 256, 256, 0, stream>>>(seg_sum, NB * HH);
  trunk_kernel<<<NTOT / ROWS, THREADS, 0, stream>>>(nodes, coord_seg,
                                                    tw0, tb0, wt_tw1, tb1, wt_tw2, tb2,
                                                    seg_sum);
  mean_kernel<<<NB, 256, 0, stream>>>(seg_sum, coord_seg, seg_mean);
  branch_kernel<<<NTOT / ROWS, THREADS, 0, stream>>>(known_nodes, known_seg,
                                                     bw0, bb0, wt_bw1, bb1, wt_bw2, bb2,
                                                     seg_mean,
                                                     wt_ow0, ob0, ow1, ob1,
                                                     out);
}

// Round 17
// 253.501 us; speedup vs baseline: 1.5645x; 1.5645x over previous
//
#include <hip/hip_runtime.h>

#define HH 256       // hidden size
#define NB 64        // batch (segments)
#define ROWS 64      // rows per block tile
#define NTOT 262144  // NK == NC
#define THREADS 256  // 4 waves

typedef _Float16 half8 __attribute__((ext_vector_type(8)));
typedef _Float16 half4 __attribute__((ext_vector_type(4)));
typedef float f32x4 __attribute__((ext_vector_type(4)));

typedef __attribute__((address_space(1))) const void gas_t;
typedef __attribute__((address_space(3))) void las_t;

// act LDS tile: [row][k] fp16, 64 rows x 256 k = 32KB, row stride 512B.
__device__ __forceinline__ uint32_t swz(uint32_t r, uint32_t k) {
  return (((r << 9) + (k << 1)) ^ ((r & 7) << 4)) ^ ((r & 8) << 3);
}

// Stage one wave-private 4KB A-slab (64 j x 32 k): 4 DMA calls x 1KB.
__device__ __forceinline__ void stage_slab(const char* __restrict__ g, char* l,
                                           int lane)
{
  const char* gp = g + lane * 16;
#pragma unroll
  for (int c = 0; c < 4; ++c)
    __builtin_amdgcn_global_load_lds((gas_t*)(gp + c * 1024), (las_t*)(l + c * 1024),
                                     16, 0, 0);
}

// ---------------------------------------------------------------------------
// Heavy layer via MFMA, swapped operands: D[j][r] = sum_k WT[j][k]*act[r][k]
// A from wave-private LDS slabs (async DMA, 3-deep, counted per-wave vmcnt).
// *** R17: BOTH operands double-buffered in registers *** — during MFMA(ks),
// the a(ks+1) AND b(ks+1) ds_reads are already in flight (R15 prefetched only
// b; the a-reads stayed on the critical path -> null). The compiler's precise
// lgkmcnt(8) gate before MFMA(ks+1) is then already satisfied: the ~150cy LDS
// latency per ks step disappears from the critical path. Full unroll makes
// ks compile-time -> a[ks&1]/b[ks&1] are statically indexed (rule 20).
// MODE: 0 relu; 1 plain (trunk c); 2 multiply seg_mean[seg_g[r]] (branch)
// ---------------------------------------------------------------------------
template<int MODE>
__device__ __forceinline__ void heavy_layer(char* act, char* wpan,
                                            const char* __restrict__ wt3,
                                            const float* __restrict__ bias,
                                            const float* __restrict__ seg_mean,
                                            const int* __restrict__ seg_g, int tid)
{
  const int wid  = tid >> 6;
  const int lane = tid & 63;
  const int lr   = lane & 15;
  const int lg   = lane >> 4;
  const int j0   = wid << 6;
  char* slab = wpan + wid * 12288;           // three private 4KB buffers
  const char* wsrc = wt3 + wid * 4096;       // + ks*16KB

  f32x4 acc[4][4];  // [jf][rf]
#pragma unroll
  for (int jf = 0; jf < 4; ++jf)
#pragma unroll
    for (int rf = 0; rf < 4; ++rf)
      acc[jf][rf] = (f32x4){0.f, 0.f, 0.f, 0.f};

  // prologue: slabs for ks=0,1,2 in flight (12 DMA ops)
  stage_slab(wsrc + 0 * 16384, slab + 0 * 4096, lane);
  stage_slab(wsrc + 1 * 16384, slab + 1 * 4096, lane);
  stage_slab(wsrc + 2 * 16384, slab + 2 * 4096, lane);

  half8 a[2][4], b[2][4];  // double-buffered operand fragments

  // wait slab0 (slabs 1,2 = 8 DMAs may remain), load ks=0 operands
  asm volatile("s_waitcnt vmcnt(8)" ::: "memory");
  __builtin_amdgcn_sched_barrier(0);
#pragma unroll
  for (int rf = 0; rf < 4; ++rf)
    b[0][rf] = *(const half8*)(act + swz(rf * 16 + lr, 0 * 32 + lg * 8));
#pragma unroll
  for (int jf = 0; jf < 4; ++jf)
    a[0][jf] = *(const half8*)(slab + 0 * 4096 + jf * 1024 + lane * 16);

#pragma unroll
  for (int ks = 0; ks < 8; ++ks) {
    const int p = ks & 1;
    if (ks < 7) {
      // slab ks+1 resident check: issued slabs reach ks+2 -> allow 4 in flight
      if (ks < 6) asm volatile("s_waitcnt vmcnt(4)" ::: "memory");
      else        asm volatile("s_waitcnt vmcnt(0)" ::: "memory");
      __builtin_amdgcn_sched_barrier(0);
      // issue next-step operand reads; latency hides under this step's MFMAs
#pragma unroll
      for (int rf = 0; rf < 4; ++rf)
        b[p ^ 1][rf] = *(const half8*)(act + swz(rf * 16 + lr, (ks + 1) * 32 + lg * 8));
#pragma unroll
      for (int jf = 0; jf < 4; ++jf)
        a[p ^ 1][jf] = *(const half8*)(slab + ((ks + 1) % 3) * 4096 + jf * 1024 + lane * 16);
    }
    __builtin_amdgcn_sched_barrier(0);  // pin nxt-reads before the MFMA cluster
#pragma unroll
    for (int jf = 0; jf < 4; ++jf)
#pragma unroll
      for (int rf = 0; rf < 4; ++rf)
        acc[jf][rf] = __builtin_amdgcn_mfma_f32_16x16x32_f16(a[p][jf], b[p][rf], acc[jf][rf], 0, 0, 0);
    __builtin_amdgcn_sched_barrier(0);  // pin DMA refill after cur-reads retired
    if (ks < 5)
      stage_slab(wsrc + (ks + 3) * 16384, slab + (ks % 3) * 4096, lane);
  }
  // all own DMAs retired (vmcnt 0 at ks=6 wait), all own act reads done.

  int sseg[4];
  if (MODE == 2) {
#pragma unroll
    for (int rf = 0; rf < 4; ++rf) sseg[rf] = seg_g[rf * 16 + lr];
  }

  __syncthreads();  // all waves done READING act before overwrite

#pragma unroll
  for (int jf = 0; jf < 4; ++jf) {
    f32x4 bj = *(const f32x4*)(bias + j0 + jf * 16 + lg * 4);
#pragma unroll
    for (int rf = 0; rf < 4; ++rf) {
      f32x4 v = acc[jf][rf] + bj;
      if (MODE == 2) {
        f32x4 sm = *(const f32x4*)(seg_mean + sseg[rf] * HH + j0 + jf * 16 + lg * 4);
        v *= sm;
      }
      half4 h;
#pragma unroll
      for (int u = 0; u < 4; ++u) {
        float x = v[u];
        if (MODE == 0) x = fmaxf(x, 0.f);
        h[u] = (_Float16)x;
      }
      *(half4*)(act + swz(rf * 16 + lr, j0 + jf * 16 + lg * 4)) = h;
    }
  }
  __syncthreads();  // act tile complete for next layer
}

// layer 1 via MFMA: F=3 -> H (relu), K padded 3 -> 32 with zeros.
__device__ __forceinline__ void layer1_mfma(char* act, const float* __restrict__ x,
                                            int r0g, const float* __restrict__ W0,
                                            const float* __restrict__ b0, int tid)
{
  const int wid  = tid >> 6;
  const int lane = tid & 63;
  const int lr   = lane & 15;
  const int lg   = lane >> 4;
  const int j0   = wid << 6;

  half8 a[4];
#pragma unroll
  for (int jf = 0; jf < 4; ++jf) {
    half8 v = {0, 0, 0, 0, 0, 0, 0, 0};
    if (lg == 0) {
      int j = j0 + jf * 16 + lr;
      v[0] = (_Float16)W0[j];
      v[1] = (_Float16)W0[HH + j];
      v[2] = (_Float16)W0[2 * HH + j];
    }
    a[jf] = v;
  }

  f32x4 acc[4][4];
#pragma unroll
  for (int jf = 0; jf < 4; ++jf)
#pragma unroll
    for (int rf = 0; rf < 4; ++rf)
      acc[jf][rf] = (f32x4){0.f, 0.f, 0.f, 0.f};

#pragma unroll
  for (int rf = 0; rf < 4; ++rf) {
    half8 b = {0, 0, 0, 0, 0, 0, 0, 0};
    if (lg == 0) {
      const float* xp = x + (size_t)(r0g + rf * 16 + lr) * 3;
      b[0] = (_Float16)xp[0];
      b[1] = (_Float16)xp[1];
      b[2] = (_Float16)xp[2];
    }
#pragma unroll
    for (int jf = 0; jf < 4; ++jf)
      acc[jf][rf] = __builtin_amdgcn_mfma_f32_16x16x32_f16(a[jf], b, acc[jf][rf], 0, 0, 0);
  }

#pragma unroll
  for (int jf = 0; jf < 4; ++jf) {
    f32x4 bj = *(const f32x4*)(b0 + j0 + jf * 16 + lg * 4);
#pragma unroll
    for (int rf = 0; rf < 4; ++rf) {
      f32x4 v = acc[jf][rf] + bj;
      half4 h;
#pragma unroll
      for (int u = 0; u < 4; ++u)
        h[u] = (_Float16)fmaxf(v[u], 0.f);
      *(half4*)(act + swz(rf * 16 + lr, j0 + jf * 16 + lg * 4)) = h;
    }
  }
  __syncthreads();
}

// ---------------------------------------------------------------------------
__global__ __launch_bounds__(THREADS, 2)
void trunk_kernel(const float* __restrict__ nodes, const int* __restrict__ coord_seg,
                  const float* __restrict__ tw0, const float* __restrict__ tb0,
                  const char* __restrict__ wt3_1, const float* __restrict__ tb1,
                  const char* __restrict__ wt3_2, const float* __restrict__ tb2,
                  float* __restrict__ seg_sum)
{
  __shared__ __align__(16) char act[ROWS * HH * 2];   // 32KB
  __shared__ __align__(16) char wpan[4 * 12288];      // 48KB, wave-private x3
  const int tid = threadIdx.x;
  const int r0g = blockIdx.x * ROWS;

  layer1_mfma(act, nodes, r0g, tw0, tb0, tid);
  heavy_layer<0>(act, wpan, wt3_1, tb1, nullptr, nullptr, tid);
  heavy_layer<1>(act, wpan, wt3_2, tb2, nullptr, nullptr, tid);  // c

  // per-segment sums of c; segs sorted -> most tiles single-segment.
  {
    const int j = tid;
    const int s_lo = coord_seg[r0g];
    const int s_hi = coord_seg[r0g + ROWS - 1];
    if (s_lo == s_hi) {
      float p = 0.f;
#pragma unroll 8
      for (int r = 0; r < ROWS; ++r)
        p += (float)*(const _Float16*)(act + swz(r, j));
      atomicAdd(&seg_sum[s_lo * HH + j], p);
    } else {
      for (int s = s_lo; s <= s_hi; ++s) {
        float p = 0.f;
        for (int r = 0; r < ROWS; ++r)
          if (coord_seg[r0g + r] == s)
            p += (float)*(const _Float16*)(act + swz(r, j));
        atomicAdd(&seg_sum[s * HH + j], p);
      }
    }
  }
}

__global__ __launch_bounds__(THREADS, 2)
void branch_kernel(const float* __restrict__ known_nodes, const int* __restrict__ known_seg,
                   const float* __restrict__ bw0, const float* __restrict__ bb0,
                   const char* __restrict__ wt3_1, const float* __restrict__ bb1,
                   const char* __restrict__ wt3_2, const float* __restrict__ bb2,
                   const float* __restrict__ seg_mean,
                   const char* __restrict__ wt3_o, const float* __restrict__ ob0,
                   const float* __restrict__ ow1, const float* __restrict__ ob1,
                   float* __restrict__ out)
{
  __shared__ __align__(16) char act[ROWS * HH * 2];   // 32KB
  __shared__ __align__(16) char wpan[4 * 12288];      // 48KB; tail reuses as ps
  const int tid = threadIdx.x;
  const int r0g = blockIdx.x * ROWS;

  layer1_mfma(act, known_nodes, r0g, bw0, bb0, tid);
  heavy_layer<0>(act, wpan, wt3_1, bb1, nullptr, nullptr, tid);
  heavy_layer<2>(act, wpan, wt3_2, bb2, seg_mean, known_seg + r0g, tid);
  heavy_layer<0>(act, wpan, wt3_o, ob0, nullptr, nullptr, tid);

  // out = h @ ow1 + ob1 (256 -> 3): 256 threads, 4 k-quarters in parallel.
  // ps reuses wpan (all DMAs retired, panel data dead).
  float* ps = (float*)wpan;
  {
    const int r = tid & 63;
    const int q = tid >> 6;
    float o0 = 0.f, o1 = 0.f, o2 = 0.f;
    for (int kk = 0; kk < 64; kk += 8) {
      int k0 = q * 64 + kk;
      half8 h = *(const half8*)(act + swz(r, k0));
#pragma unroll
      for (int u = 0; u < 8; ++u) {
        float a = (float)h[u];
        o0 = fmaf(a, ow1[(k0 + u) * 3 + 0], o0);
        o1 = fmaf(a, ow1[(k0 + u) * 3 + 1], o1);
        o2 = fmaf(a, ow1[(k0 + u) * 3 + 2], o2);
      }
    }
    float* p = ps + q * ROWS * 3;
    p[r * 3 + 0] = o0; p[r * 3 + 1] = o1; p[r * 3 + 2] = o2;
  }
  __syncthreads();
  if (tid < ROWS) {
    const int r = tid;
    float* dst = out + (size_t)(r0g + r) * 3;
#pragma unroll
    for (int c = 0; c < 3; ++c) {
      float o = ob1[c];
#pragma unroll
      for (int q = 0; q < 4; ++q) o += ps[q * ROWS * 3 + r * 3 + c];
      dst[c] = o;
    }
  }
}

// W[256][256] fp32 (row=k, col=j) -> WT3 slab-linear fp16:
// off = ks*16KB + wq*4KB + jf*1KB + (lg*16+lr)*16 + kk*2
//   where jf=(j>>4)&3, lr=j&15, lg=(k>>3)&3, kk=k&7.
struct WPtrs { const float* w[5]; char* wt3[5]; };
__global__ void transpose_kernel(WPtrs p)
{
  const int m = blockIdx.x >> 8;   // matrix
  const int k = blockIdx.x & 255;  // input dim
  const int j = threadIdx.x;       // output dim
  size_t off = (size_t)(k >> 5) * 16384 + (size_t)(j >> 6) * 4096
             + (size_t)((j >> 4) & 3) * 1024
             + (size_t)((((k >> 3) & 3) << 4) | (j & 15)) * 16
             + (size_t)(k & 7) * 2;
  *(_Float16*)(p.wt3[m] + off) = (_Float16)p.w[m][k * HH + j];
}

__global__ void zero_kernel(float* __restrict__ p, int n)
{
  int i = blockIdx.x * blockDim.x + threadIdx.x;
  if (i < n) p[i] = 0.f;
}

__global__ void mean_kernel(const float* __restrict__ seg_sum,
                            const int* __restrict__ coord_seg,
                            float* __restrict__ seg_mean)
{
  const int b = blockIdx.x;
  int lo = 0, n = NTOT;
  while (n > 0) { int h = n >> 1; int mid = lo + h;
    if (coord_seg[mid] < b) { lo = mid + 1; n -= h + 1; } else n = h; }
  int hi = lo; n = NTOT - lo;
  while (n > 0) { int h = n >> 1; int mid = hi + h;
    if (coord_seg[mid] < b + 1) { hi = mid + 1; n -= h + 1; } else n = h; }
  float inv = 1.0f / fmaxf((float)(hi - lo), 1.0f);
  seg_mean[b * HH + threadIdx.x] = seg_sum[b * HH + threadIdx.x] * inv;
}

// ---------------------------------------------------------------------------
extern "C" void kernel_launch(void* const* d_in, const int* in_sizes, int n_in,
                              void* d_out, int out_size, void* d_ws, size_t ws_size,
                              hipStream_t stream)
{
  const float* known_nodes = (const float*)d_in[0];
  const float* nodes       = (const float*)d_in[1];
  const int*   known_seg   = (const int*)d_in[2];
  const int*   coord_seg   = (const int*)d_in[3];
  const float* bw0 = (const float*)d_in[4];
  const float* bb0 = (const float*)d_in[5];
  const float* bw1 = (const float*)d_in[6];
  const float* bb1 = (const float*)d_in[7];
  const float* bw2 = (const float*)d_in[8];
  const float* bb2 = (const float*)d_in[9];
  const float* tw0 = (const float*)d_in[10];
  const float* tb0 = (const float*)d_in[11];
  const float* tw1 = (const float*)d_in[12];
  const float* tb1 = (const float*)d_in[13];
  const float* tw2 = (const float*)d_in[14];
  const float* tb2 = (const float*)d_in[15];
  const float* ow0 = (const float*)d_in[16];
  const float* ob0 = (const float*)d_in[17];
  const float* ow1 = (const float*)d_in[18];
  const float* ob1 = (const float*)d_in[19];

  float* out      = (float*)d_out;
  float* seg_sum  = (float*)d_ws;                        // [64][256] f32
  float* seg_mean = seg_sum + NB * HH;                   // [64][256] f32
  char* wt3b      = (char*)d_ws + (size_t)2 * NB * HH * 4;
  char* wt3_tw1 = wt3b + 0 * (size_t)HH * HH * 2;
  char* wt3_tw2 = wt3b + 1 * (size_t)HH * HH * 2;
  char* wt3_bw1 = wt3b + 2 * (size_t)HH * HH * 2;
  char* wt3_bw2 = wt3b + 3 * (size_t)HH * HH * 2;
  char* wt3_ow0 = wt3b + 4 * (size_t)HH * HH * 2;

  WPtrs wp;
  wp.w[0] = tw1; wp.wt3[0] = wt3_tw1;
  wp.w[1] = tw2; wp.wt3[1] = wt3_tw2;
  wp.w[2] = bw1; wp.wt3[2] = wt3_bw1;
  wp.w[3] = bw2; wp.wt3[3] = wt3_bw2;
  wp.w[4] = ow0; wp.wt3[4] = wt3_ow0;

  transpose_kernel<<<5 * 256, 256, 0, stream>>>(wp);
  zero_kernel<<<(NB * HH + 255) / 256, 256, 0, stream>>>(seg_sum, NB * HH);
  trunk_kernel<<<NTOT / ROWS, THREADS, 0, stream>>>(nodes, coord_seg,
                                                    tw0, tb0, wt3_tw1, tb1, wt3_tw2, tb2,
                                                    seg_sum);
  mean_kernel<<<NB, 256, 0, stream>>>(seg_sum, coord_seg, seg_mean);
  branch_kernel<<<NTOT / ROWS, THREADS, 0, stream>>>(known_nodes, known_seg,
                                                     bw0, bb0, wt3_bw1, bb1, wt3_bw2, bb2,
                                                     seg_mean,
                                                     wt3_ow0, ob0, ow1, ob1,
                                                     out);
}